// Round 13
// baseline (525.931 us; speedup 1.0000x reference)
//
#include <hip/hip_runtime.h>
#include <hip/hip_bf16.h>
#include <math.h>

#define NN 50000
#define DD 128
#define RR 16
#define NBASIS 10
#define NE 1600000
#define NSEG (NN * RR)                  // 800000 segments (dst,rel)
#define NPART ((NSEG + 1023) / 1024)    // 782
#define KTOT 2304                       // 18*128: 16 rel + time + root/x
#define DECAY 0.1f
#define EDGE_BLOCKS ((NE + 1023) / 1024)   // 1563: 4 edges/thread, 256 thr

typedef short bf16x8 __attribute__((ext_vector_type(8)));
typedef float f32x4 __attribute__((ext_vector_type(4)));
typedef int   i32x4 __attribute__((ext_vector_type(4)));   // native vec for nt builtins
typedef float fv4   __attribute__((ext_vector_type(4)));

__device__ __forceinline__ ushort f2b(float f) {
    unsigned u = __float_as_uint(f);
    unsigned r = (u + 0x7FFFu + ((u >> 16) & 1u)) >> 16;
    return (ushort)r;
}
__device__ __forceinline__ float b2f(ushort u) {
    return __uint_as_float(((unsigned)u) << 16);
}

// ---------------- reduction slots ----------------
__global__ void k_init(unsigned* red) {
    if (threadIdx.x == 0) {
        red[0] = 0u;              // max(t) bits (t>=0: uint order == float order)
        red[1] = 0x7F800000u;     // min(t) = +inf
        ((float*)red)[2] = 0.0f;  // sum of unnormalized w
    }
}

// ---------------- 4 edges/thread: edge_time min/max + segment histogram ----------------
// Vector nt loads; 4 independent fire-and-forget atomics per thread.
__global__ __launch_bounds__(256) void k_pre1(const float* __restrict__ t,
                                              const int* __restrict__ edst,
                                              const int* __restrict__ etype,
                                              unsigned* __restrict__ red,
                                              unsigned* __restrict__ cnt) {
    __shared__ float smx[4], smn[4];
    const int tid = threadIdx.x;
    const int base = (blockIdx.x * 256 + tid) * 4;   // NE%4==0 -> no partial vec
    float mx = 0.0f, mn = 1e30f;
    if (base < NE) {
        fv4 tv   = __builtin_nontemporal_load((const fv4*)(t + base));
        i32x4 dv = __builtin_nontemporal_load((const i32x4*)(edst + base));
        i32x4 yv = __builtin_nontemporal_load((const i32x4*)(etype + base));
        mx = fmaxf(fmaxf(tv.x, tv.y), fmaxf(tv.z, tv.w));
        mn = fminf(fminf(tv.x, tv.y), fminf(tv.z, tv.w));
        atomicAdd(&cnt[dv.x * RR + yv.x], 1u);
        atomicAdd(&cnt[dv.y * RR + yv.y], 1u);
        atomicAdd(&cnt[dv.z * RR + yv.z], 1u);
        atomicAdd(&cnt[dv.w * RR + yv.w], 1u);
    }
    for (int o = 32; o >= 1; o >>= 1) {
        mx = fmaxf(mx, __shfl_down(mx, o, 64));
        mn = fminf(mn, __shfl_down(mn, o, 64));
    }
    if ((tid & 63) == 0) { smx[tid >> 6] = mx; smn[tid >> 6] = mn; }
    __syncthreads();
    if (tid == 0) {
        mx = fmaxf(fmaxf(smx[0], smx[1]), fmaxf(smx[2], smx[3]));
        mn = fminf(fminf(smn[0], smn[1]), fminf(smn[2], smn[3]));
        atomicMax(&red[0], __float_as_uint(mx));
        atomicMin(&red[1], __float_as_uint(mn));
    }
}

// ---------------- hierarchical exclusive scan over cnt[NSEG] ----------------
__global__ __launch_bounds__(1024) void k_scan1(const unsigned* __restrict__ cnt,
                                                unsigned* __restrict__ segptr,
                                                unsigned* __restrict__ part) {
    __shared__ unsigned sh[1024];
    int tid = threadIdx.x;
    int i = blockIdx.x * 1024 + tid;
    unsigned v = (i < NSEG) ? cnt[i] : 0u;
    sh[tid] = v;
    __syncthreads();
    for (int off = 1; off < 1024; off <<= 1) {
        unsigned t = (tid >= off) ? sh[tid - off] : 0u;
        __syncthreads();
        sh[tid] += t;
        __syncthreads();
    }
    if (i < NSEG) segptr[i] = sh[tid] - v;       // exclusive, block-local
    if (tid == 1023) part[blockIdx.x] = sh[1023];
}

__global__ __launch_bounds__(1024) void k_scan2(unsigned* __restrict__ part) {
    __shared__ unsigned sh[1024];
    int tid = threadIdx.x;
    unsigned v = (tid < NPART) ? part[tid] : 0u;
    sh[tid] = v;
    __syncthreads();
    for (int off = 1; off < 1024; off <<= 1) {
        unsigned t = (tid >= off) ? sh[tid - off] : 0u;
        __syncthreads();
        sh[tid] += t;
        __syncthreads();
    }
    if (tid < NPART) part[tid] = sh[tid] - v;    // exclusive
}

__global__ __launch_bounds__(1024) void k_scan3(unsigned* __restrict__ segptr,
                                                const unsigned* __restrict__ part) {
    int i = blockIdx.x * 1024 + threadIdx.x;
    if (i < NSEG) segptr[i] += part[i >> 10];
}

// ---------------- 4 edges/thread: sum of weights + reorder into packed records ----------------
// record = src (low 16) | bf16(w) (high 16). After this kernel segptr[s] = END of seg s.
// 4 independent atomic->store chains per thread (4x MLP on the latency chain).
__global__ __launch_bounds__(256) void k_pre2(const int* __restrict__ esrc,
                                              const int* __restrict__ edst,
                                              const int* __restrict__ etype,
                                              const float* __restrict__ etime,
                                              unsigned* __restrict__ red,
                                              unsigned* __restrict__ segptr,
                                              unsigned* __restrict__ srcw) {
    __shared__ float ssum[4];
    const int tid = threadIdx.x;
    const float tmax = __uint_as_float(red[0]);
    const float tmin = __uint_as_float(red[1]);
    const float rtd = -DECAY / (tmax - tmin + 1e-8f);
    const int base = (blockIdx.x * 256 + tid) * 4;
    float s = 0.0f;
    if (base < NE) {
        i32x4 sv = __builtin_nontemporal_load((const i32x4*)(esrc + base));
        i32x4 dv = __builtin_nontemporal_load((const i32x4*)(edst + base));
        i32x4 yv = __builtin_nontemporal_load((const i32x4*)(etype + base));
        fv4 tv   = __builtin_nontemporal_load((const fv4*)(etime + base));
        float w0 = expf((tmax - tv.x) * rtd);
        float w1 = expf((tmax - tv.y) * rtd);
        float w2 = expf((tmax - tv.z) * rtd);
        float w3 = expf((tmax - tv.w) * rtd);
        s = (w0 + w1) + (w2 + w3);
        unsigned p0 = atomicAdd(&segptr[dv.x * RR + yv.x], 1u);
        unsigned p1 = atomicAdd(&segptr[dv.y * RR + yv.y], 1u);
        unsigned p2 = atomicAdd(&segptr[dv.z * RR + yv.z], 1u);
        unsigned p3 = atomicAdd(&segptr[dv.w * RR + yv.w], 1u);
        srcw[p0] = (unsigned)(sv.x & 0xFFFF) | ((unsigned)f2b(w0) << 16);
        srcw[p1] = (unsigned)(sv.y & 0xFFFF) | ((unsigned)f2b(w1) << 16);
        srcw[p2] = (unsigned)(sv.z & 0xFFFF) | ((unsigned)f2b(w2) << 16);
        srcw[p3] = (unsigned)(sv.w & 0xFFFF) | ((unsigned)f2b(w3) << 16);
    }
    for (int o = 32; o >= 1; o >>= 1) s += __shfl_down(s, o, 64);
    if ((tid & 63) == 0) ssum[tid >> 6] = s;
    __syncthreads();
    if (tid == 0)
        atomicAdd(((float*)red) + 2, ssum[0] + ssum[1] + ssum[2] + ssum[3]);
}

// ---------------- fused: x->bf16 and build Bt3[j][k] bf16 (k = r*128+d) ----------------
#define XB_ITEMS (NN * (DD / 4))
__global__ __launch_bounds__(256) void k_prep(const float* __restrict__ x,
                                              const float* __restrict__ basis,
                                              const float* __restrict__ comp,
                                              const float* __restrict__ root,
                                              const float* __restrict__ tp_w,
                                              ushort* __restrict__ xb,
                                              ushort* __restrict__ Bt3) {
    int idx = blockIdx.x * 256 + threadIdx.x;
    if (idx < XB_ITEMS) {
        float4 v = ((const float4*)x)[idx];
        ushort4 o;
        o.x = f2b(v.x); o.y = f2b(v.y); o.z = f2b(v.z); o.w = f2b(v.w);
        ((ushort4*)xb)[idx] = o;
        return;
    }
    int bidx = idx - XB_ITEMS;
    if (bidx >= DD * KTOT) return;
    int j = bidx / KTOT, k = bidx - j * KTOT;
    int r = k >> 7, d = k & 127;
    float v;
    if (r < RR) {
        v = 0.0f;
        for (int b = 0; b < NBASIS; ++b)
            v = fmaf(comp[r * NBASIS + b], basis[(b * DD + d) * DD + j], v);
    } else if (r == RR) {
        v = tp_w[d * DD + j];
    } else {
        v = root[d * DD + j];
    }
    Bt3[bidx] = f2b(v);
}

// ---------------- gather-aggregate: one wave per dst, SCALARIZED bookkeeping ----------------
__global__ __launch_bounds__(256) void k_gather(
    const ushort* __restrict__ xb, const unsigned* __restrict__ srcw,
    const unsigned* __restrict__ segptr, const unsigned* __restrict__ red,
    ushort* __restrict__ A2)
{
    const int wave = threadIdx.x >> 6, lane = threadIdx.x & 63;
    int dst0 = blockIdx.x * 4 + wave;
    if (dst0 >= NN) return;
    const int dst = __builtin_amdgcn_readfirstlane(dst0);
    const float sumw = ((const float*)red)[2];
    const unsigned s0 = (unsigned)dst * RR;
    const unsigned start = (dst == 0) ? 0u : segptr[s0 - 1];
    const unsigned endAll = segptr[s0 + RR - 1];
    const unsigned deg = endAll - start;
    unsigned* arow = (unsigned*)(A2 + (size_t)dst * KTOT);

    float a0 = 0.0f, a1 = 0.0f, xt0 = 0.0f, xt1 = 0.0f;
    int r = 0;
    unsigned scur = start;
    unsigned endr = segptr[s0];
    unsigned e = start;

#define FLUSH_REL {                                                          \
        float scl = (endr > scur) ? (1.0f / (float)(endr - scur)) : 0.0f;    \
        __builtin_nontemporal_store(                                         \
            (unsigned)f2b(a0 * scl) | ((unsigned)f2b(a1 * scl) << 16),       \
            arow + r * 64 + lane);                                           \
        a0 = 0.0f; a1 = 0.0f; scur = endr; ++r;                              \
        endr = (r < RR) ? segptr[s0 + r] : 0xFFFFFFFFu; }

#define ACCUM(rec, pv) {                                                     \
        float wgt = __uint_as_float((rec) & 0xFFFF0000u);                    \
        float vx = b2f((ushort)((pv) & 0xFFFFu));                            \
        float vy = b2f((ushort)((pv) >> 16));                                \
        a0 += vx; a1 += vy;                                                  \
        xt0 = fmaf(wgt, vx, xt0); xt1 = fmaf(wgt, vy, xt1); }

    while (e < endAll) {
        unsigned rem = endAll - e;
        int m = (rem > 4u) ? 4 : (int)rem;
        unsigned rec0 = 0, rec1 = 0, rec2 = 0, rec3 = 0;
        unsigned pv0 = 0, pv1 = 0, pv2 = 0, pv3 = 0;
        rec0 = srcw[e];
        if (m > 1) rec1 = srcw[e + 1];
        if (m > 2) rec2 = srcw[e + 2];
        if (m > 3) rec3 = srcw[e + 3];
        pv0 = ((const unsigned*)(xb + (size_t)(rec0 & 0xFFFFu) * DD))[lane];
        if (m > 1) pv1 = ((const unsigned*)(xb + (size_t)(rec1 & 0xFFFFu) * DD))[lane];
        if (m > 2) pv2 = ((const unsigned*)(xb + (size_t)(rec2 & 0xFFFFu) * DD))[lane];
        if (m > 3) pv3 = ((const unsigned*)(xb + (size_t)(rec3 & 0xFFFFu) * DD))[lane];

        while (e >= endr) FLUSH_REL;
        ACCUM(rec0, pv0); ++e;
        if (m > 1) { while (e >= endr) FLUSH_REL; ACCUM(rec1, pv1); ++e; }
        if (m > 2) { while (e >= endr) FLUSH_REL; ACCUM(rec2, pv2); ++e; }
        if (m > 3) { while (e >= endr) FLUSH_REL; ACCUM(rec3, pv3); ++e; }
    }
    while (r < RR) FLUSH_REL;

    float s2 = 1.0f / ((sumw + 1e-8f) * fmaxf((float)deg, 1.0f));
    __builtin_nontemporal_store(
        (unsigned)f2b(xt0 * s2) | ((unsigned)f2b(xt1 * s2) << 16),
        arow + RR * 64 + lane);
    __builtin_nontemporal_store(
        ((const unsigned*)(xb + (size_t)dst * DD))[lane],
        arow + (RR + 1) * 64 + lane);
#undef FLUSH_REL
#undef ACCUM
}

// ---------------- double-buffered tiled MFMA GEMM + bias/relu/LN ----------------
// Block: 256 thr / 64 rows x 128 cols, BK=64, 36 K-iters, 2x24 KB LDS ping-pong.
// One barrier per iter: barrier drains prefetch(it) issued last iter; then issue
// prefetch(it+1) into the other buffer and compute it — HBM latency overlaps
// the ds_read+MFMA phase instead of being fully exposed (r11 structure stalled).
__global__ __launch_bounds__(256) void k_fgemm(
    const ushort* __restrict__ A2, const ushort* __restrict__ Bt3,
    const float* __restrict__ bias, const float* __restrict__ tpb,
    const float* __restrict__ gamma, const float* __restrict__ beta,
    float* __restrict__ out)
{
    __shared__ unsigned As[2][2048];    // 2 x  8 KB: [row  64][8 chunks x 16B]
    __shared__ unsigned Bs[2][4096];    // 2 x 16 KB: [col 128][8 chunks x 16B]

    const int tid = threadIdx.x;
    const int w = tid >> 6, lane = tid & 63;
    const int quad = lane >> 4, l16 = lane & 15;
    const int n0 = blockIdx.x * 64;

    f32x4 acc[8];
#pragma unroll
    for (int ct = 0; ct < 8; ++ct) acc[ct] = (f32x4){0.f, 0.f, 0.f, 0.f};

    const int srow = lane >> 3;          // 0..7 within a staging inst group
    const int sc   = lane & 7;           // physical chunk

#define STAGE(buf, k0) {                                                       \
        _Pragma("unroll")                                                      \
        for (int i = 0; i < 2; ++i) {    /* A: 64 rows */                      \
            const int cid = i * 4 + w;                                         \
            const int row = cid * 8 + srow;                                    \
            const int ck  = sc ^ (row & 7);                                    \
            const ushort* ga = A2 + (size_t)(n0 + row) * KTOT + (k0) + ck * 8; \
            __builtin_amdgcn_global_load_lds(                                  \
                (const __attribute__((address_space(1))) unsigned*)ga,         \
                (__attribute__((address_space(3))) unsigned*)&As[buf][cid * 256], 16, 0, 0); \
        }                                                                      \
        _Pragma("unroll")                                                      \
        for (int i = 0; i < 4; ++i) {    /* B: 128 cols */                     \
            const int cid = i * 4 + w;                                         \
            const int row = cid * 8 + srow;                                    \
            const int ck  = sc ^ (row & 7);                                    \
            const ushort* gb = Bt3 + (size_t)row * KTOT + (k0) + ck * 8;       \
            __builtin_amdgcn_global_load_lds(                                  \
                (const __attribute__((address_space(1))) unsigned*)gb,         \
                (__attribute__((address_space(3))) unsigned*)&Bs[buf][cid * 256], 16, 0, 0); \
        }                                                                      \
    }

    STAGE(0, 0);
    const int NIT = KTOT / 64;
    for (int it = 0; it < NIT; ++it) {
        const int buf = it & 1;
        __syncthreads();                 // drains prefetch(it); guards buf^1 reuse
        if (it + 1 < NIT) STAGE(buf ^ 1, (it + 1) * 64);

        const int rA = w * 16 + l16;
        bf16x8 af[2];
#pragma unroll
        for (int h = 0; h < 2; ++h)
            af[h] = *(const bf16x8*)&As[buf][rA * 32 + (((h * 4 + quad) ^ (rA & 7)) << 2)];
#pragma unroll
        for (int ct = 0; ct < 8; ++ct) {
            const int rB = ct * 16 + l16;
            bf16x8 b0 = *(const bf16x8*)&Bs[buf][rB * 32 + ((quad ^ (rB & 7)) << 2)];
            bf16x8 b1 = *(const bf16x8*)&Bs[buf][rB * 32 + (((4 + quad) ^ (rB & 7)) << 2)];
            acc[ct] = __builtin_amdgcn_mfma_f32_16x16x32_bf16(af[0], b0, acc[ct], 0, 0, 0);
            acc[ct] = __builtin_amdgcn_mfma_f32_16x16x32_bf16(af[1], b1, acc[ct], 0, 0, 0);
        }
    }
#undef STAGE

    // ---- epilogue: bias + relu + LN (in-wave, rows rb = n0 + w*16) ----
    float bc[8], gc[8], be[8];
#pragma unroll
    for (int ct = 0; ct < 8; ++ct) {
        int col = ct * 16 + l16;
        bc[ct] = bias[col] + tpb[col];
        gc[ct] = gamma[col];
        be[ct] = beta[col];
    }
    float s[4] = {0, 0, 0, 0}, q[4] = {0, 0, 0, 0};
#pragma unroll
    for (int ct = 0; ct < 8; ++ct)
#pragma unroll
        for (int i = 0; i < 4; ++i) {
            float v = fmaxf(acc[ct][i] + bc[ct], 0.0f);
            acc[ct][i] = v;
            s[i] += v;
            q[i] = fmaf(v, v, q[i]);
        }
#pragma unroll
    for (int off = 1; off < 16; off <<= 1)
#pragma unroll
        for (int i = 0; i < 4; ++i) {
            s[i] += __shfl_xor(s[i], off, 64);
            q[i] += __shfl_xor(q[i], off, 64);
        }
#pragma unroll
    for (int i = 0; i < 4; ++i) {
        const int row = n0 + w * 16 + quad * 4 + i;
        float mu  = s[i] * (1.0f / DD);
        float var = q[i] * (1.0f / DD) - mu * mu;
        float inv = rsqrtf(var + 1e-5f);
        if (row < NN) {
#pragma unroll
            for (int ct = 0; ct < 8; ++ct)
                __builtin_nontemporal_store(
                    (acc[ct][i] - mu) * inv * gc[ct] + be[ct],
                    out + (size_t)row * DD + ct * 16 + l16);
        }
    }
}

extern "C" void kernel_launch(void* const* d_in, const int* in_sizes, int n_in,
                              void* d_out, int out_size, void* d_ws, size_t ws_size,
                              hipStream_t stream)
{
    const float* x     = (const float*)d_in[0];
    const int*   ei    = (const int*)d_in[1];
    const int*   etype = (const int*)d_in[2];
    const float* etime = (const float*)d_in[3];
    const float* basis = (const float*)d_in[4];
    const float* comp  = (const float*)d_in[5];
    const float* root  = (const float*)d_in[6];
    const float* bias  = (const float*)d_in[7];
    const float* tp_w  = (const float*)d_in[8];
    const float* tp_b  = (const float*)d_in[9];
    const float* gamma = (const float*)d_in[10];
    const float* beta  = (const float*)d_in[11];
    float* out = (float*)d_out;

    char* ws = (char*)d_ws;
    size_t off = 0;
    auto alloc = [&](size_t bytes) -> void* {
        void* p = ws + off;
        off = (off + bytes + 255) & ~(size_t)255;
        return p;
    };
    unsigned* red    = (unsigned*)alloc(64);
    unsigned* cnt    = (unsigned*)alloc((size_t)NSEG * 4);        //   3.2 MB
    unsigned* segptr = (unsigned*)alloc((size_t)NSEG * 4);        //   3.2 MB
    unsigned* part   = (unsigned*)alloc(1024 * 4);                //   4 KB
    unsigned* srcw   = (unsigned*)alloc((size_t)NE * 4);          //   6.4 MB
    ushort*   xb     = (ushort*)alloc((size_t)NN * DD * 2);       //  12.8 MB
    ushort*   Bt3    = (ushort*)alloc((size_t)DD * KTOT * 2);     //   0.59 MB
    ushort*   A2     = (ushort*)alloc((size_t)50048 * KTOT * 2);  // 230.6 MB (~256.8 MB total)
    (void)ws_size;

    const int* esrc = ei;
    const int* edst = ei + NE;

    hipLaunchKernelGGL(k_init, dim3(1), dim3(64), 0, stream, red);
    (void)hipMemsetAsync(cnt, 0, (size_t)NSEG * 4, stream);
    hipLaunchKernelGGL(k_pre1, dim3(EDGE_BLOCKS), dim3(256), 0, stream,
                       etime, edst, etype, red, cnt);

    hipLaunchKernelGGL(k_scan1, dim3(NPART), dim3(1024), 0, stream, cnt, segptr, part);
    hipLaunchKernelGGL(k_scan2, dim3(1), dim3(1024), 0, stream, part);
    hipLaunchKernelGGL(k_scan3, dim3(NPART), dim3(1024), 0, stream, segptr, part);

    hipLaunchKernelGGL(k_pre2, dim3(EDGE_BLOCKS), dim3(256), 0, stream,
                       esrc, edst, etype, etime, red, segptr, srcw);

    hipLaunchKernelGGL(k_prep, dim3((XB_ITEMS + DD * KTOT + 255) / 256), dim3(256), 0, stream,
                       x, basis, comp, root, tp_w, xb, Bt3);

    hipLaunchKernelGGL(k_gather, dim3((NN + 3) / 4), dim3(256), 0, stream,
                       xb, srcw, segptr, red, A2);

    hipLaunchKernelGGL(k_fgemm, dim3((50048 + 63) / 64), dim3(256), 0, stream,
                       A2, Bt3, bias, tp_b, gamma, beta, out);
}

// Round 14
// 482.117 us; speedup vs baseline: 1.0909x; 1.0909x over previous
//
#include <hip/hip_runtime.h>
#include <hip/hip_bf16.h>
#include <math.h>

#define NN 50000
#define DD 128
#define RR 16
#define NBASIS 10
#define NE 1600000
#define NSEG (NN * RR)                  // 800000 segments (dst,rel)
#define NPART ((NSEG + 1023) / 1024)    // 782
#define KTOT 2304                       // 18*128: 16 rel + time + root/x
#define DECAY 0.1f

typedef short bf16x8 __attribute__((ext_vector_type(8)));
typedef float f32x4 __attribute__((ext_vector_type(4)));

__device__ __forceinline__ ushort f2b(float f) {
    unsigned u = __float_as_uint(f);
    unsigned r = (u + 0x7FFFu + ((u >> 16) & 1u)) >> 16;
    return (ushort)r;
}
__device__ __forceinline__ float b2f(ushort u) {
    return __uint_as_float(((unsigned)u) << 16);
}

// ---------------- reduction slots ----------------
__global__ void k_init(unsigned* red) {
    if (threadIdx.x == 0) {
        red[0] = 0u;              // max(t) bits (t>=0: uint order == float order)
        red[1] = 0x7F800000u;     // min(t) = +inf
        ((float*)red)[2] = 0.0f;  // sum of unnormalized w
    }
}

// ---------------- grid-stride: edge_time min/max + segment histogram ----------------
// r11-proven form: 1024 blocks, one fire-and-forget atomic per edge per iter.
// (r13 lesson: 4-burst atomics per thread REGRESS scattered-atomic throughput.)
__global__ __launch_bounds__(256) void k_pre1(const float* __restrict__ t,
                                              const int* __restrict__ edst,
                                              const int* __restrict__ etype,
                                              unsigned* __restrict__ red,
                                              unsigned* __restrict__ cnt) {
    __shared__ float smx[4], smn[4];
    const int tid = threadIdx.x;
    float mx = 0.0f, mn = 1e30f;
    const int stride = gridDim.x * 256;
    for (int e = blockIdx.x * 256 + tid; e < NE; e += stride) {
        float v = __builtin_nontemporal_load(t + e);
        int d   = __builtin_nontemporal_load(edst + e);
        int ty  = __builtin_nontemporal_load(etype + e);
        mx = fmaxf(mx, v);
        mn = fminf(mn, v);
        atomicAdd(&cnt[d * RR + ty], 1u);
    }
    for (int o = 32; o >= 1; o >>= 1) {
        mx = fmaxf(mx, __shfl_down(mx, o, 64));
        mn = fminf(mn, __shfl_down(mn, o, 64));
    }
    if ((tid & 63) == 0) { smx[tid >> 6] = mx; smn[tid >> 6] = mn; }
    __syncthreads();
    if (tid == 0) {
        mx = fmaxf(fmaxf(smx[0], smx[1]), fmaxf(smx[2], smx[3]));
        mn = fminf(fminf(smn[0], smn[1]), fminf(smn[2], smn[3]));
        atomicMax(&red[0], __float_as_uint(mx));
        atomicMin(&red[1], __float_as_uint(mn));
    }
}

// ---------------- hierarchical exclusive scan over cnt[NSEG] ----------------
__global__ __launch_bounds__(1024) void k_scan1(const unsigned* __restrict__ cnt,
                                                unsigned* __restrict__ segptr,
                                                unsigned* __restrict__ part) {
    __shared__ unsigned sh[1024];
    int tid = threadIdx.x;
    int i = blockIdx.x * 1024 + tid;
    unsigned v = (i < NSEG) ? cnt[i] : 0u;
    sh[tid] = v;
    __syncthreads();
    for (int off = 1; off < 1024; off <<= 1) {
        unsigned t = (tid >= off) ? sh[tid - off] : 0u;
        __syncthreads();
        sh[tid] += t;
        __syncthreads();
    }
    if (i < NSEG) segptr[i] = sh[tid] - v;       // exclusive, block-local
    if (tid == 1023) part[blockIdx.x] = sh[1023];
}

__global__ __launch_bounds__(1024) void k_scan2(unsigned* __restrict__ part) {
    __shared__ unsigned sh[1024];
    int tid = threadIdx.x;
    unsigned v = (tid < NPART) ? part[tid] : 0u;
    sh[tid] = v;
    __syncthreads();
    for (int off = 1; off < 1024; off <<= 1) {
        unsigned t = (tid >= off) ? sh[tid - off] : 0u;
        __syncthreads();
        sh[tid] += t;
        __syncthreads();
    }
    if (tid < NPART) part[tid] = sh[tid] - v;    // exclusive
}

__global__ __launch_bounds__(1024) void k_scan3(unsigned* __restrict__ segptr,
                                                const unsigned* __restrict__ part) {
    int i = blockIdx.x * 1024 + threadIdx.x;
    if (i < NSEG) segptr[i] += part[i >> 10];
}

// ---------------- grid-stride: sum of weights + reorder into packed records ----------------
// r11-proven form. record = src(16) | bf16(w)(16). After: segptr[s] = END of seg s.
__global__ __launch_bounds__(256) void k_pre2(const int* __restrict__ esrc,
                                              const int* __restrict__ edst,
                                              const int* __restrict__ etype,
                                              const float* __restrict__ etime,
                                              unsigned* __restrict__ red,
                                              unsigned* __restrict__ segptr,
                                              unsigned* __restrict__ srcw) {
    __shared__ float ssum[4];
    const int tid = threadIdx.x;
    const float tmax = __uint_as_float(red[0]);
    const float tmin = __uint_as_float(red[1]);
    const float rtd = -DECAY / (tmax - tmin + 1e-8f);
    float s = 0.0f;
    const int stride = gridDim.x * 256;
    for (int e = blockIdx.x * 256 + tid; e < NE; e += stride) {
        float tv = __builtin_nontemporal_load(etime + e);
        int sv   = __builtin_nontemporal_load(esrc + e);
        int dv   = __builtin_nontemporal_load(edst + e);
        int yv   = __builtin_nontemporal_load(etype + e);
        float w = expf((tmax - tv) * rtd);
        s += w;
        int seg = dv * RR + yv;
        unsigned pos = atomicAdd(&segptr[seg], 1u);
        srcw[pos] = (unsigned)(sv & 0xFFFF) | ((unsigned)f2b(w) << 16);
    }
    for (int o = 32; o >= 1; o >>= 1) s += __shfl_down(s, o, 64);
    if ((tid & 63) == 0) ssum[tid >> 6] = s;
    __syncthreads();
    if (tid == 0)
        atomicAdd(((float*)red) + 2, ssum[0] + ssum[1] + ssum[2] + ssum[3]);
}

// ---------------- fused: x->bf16 and build Bt3[j][k] bf16 (k = r*128+d) ----------------
#define XB_ITEMS (NN * (DD / 4))
__global__ __launch_bounds__(256) void k_prep(const float* __restrict__ x,
                                              const float* __restrict__ basis,
                                              const float* __restrict__ comp,
                                              const float* __restrict__ root,
                                              const float* __restrict__ tp_w,
                                              ushort* __restrict__ xb,
                                              ushort* __restrict__ Bt3) {
    int idx = blockIdx.x * 256 + threadIdx.x;
    if (idx < XB_ITEMS) {
        float4 v = ((const float4*)x)[idx];
        ushort4 o;
        o.x = f2b(v.x); o.y = f2b(v.y); o.z = f2b(v.z); o.w = f2b(v.w);
        ((ushort4*)xb)[idx] = o;
        return;
    }
    int bidx = idx - XB_ITEMS;
    if (bidx >= DD * KTOT) return;
    int j = bidx / KTOT, k = bidx - j * KTOT;
    int r = k >> 7, d = k & 127;
    float v;
    if (r < RR) {
        v = 0.0f;
        for (int b = 0; b < NBASIS; ++b)
            v = fmaf(comp[r * NBASIS + b], basis[(b * DD + d) * DD + j], v);
    } else if (r == RR) {
        v = tp_w[d * DD + j];
    } else {
        v = root[d * DD + j];
    }
    Bt3[bidx] = f2b(v);
}

// ---------------- gather-aggregate: one wave per dst, SCALARIZED bookkeeping ----------------
__global__ __launch_bounds__(256) void k_gather(
    const ushort* __restrict__ xb, const unsigned* __restrict__ srcw,
    const unsigned* __restrict__ segptr, const unsigned* __restrict__ red,
    ushort* __restrict__ A2)
{
    const int wave = threadIdx.x >> 6, lane = threadIdx.x & 63;
    int dst0 = blockIdx.x * 4 + wave;
    if (dst0 >= NN) return;
    const int dst = __builtin_amdgcn_readfirstlane(dst0);
    const float sumw = ((const float*)red)[2];
    const unsigned s0 = (unsigned)dst * RR;
    const unsigned start = (dst == 0) ? 0u : segptr[s0 - 1];
    const unsigned endAll = segptr[s0 + RR - 1];
    const unsigned deg = endAll - start;
    unsigned* arow = (unsigned*)(A2 + (size_t)dst * KTOT);

    float a0 = 0.0f, a1 = 0.0f, xt0 = 0.0f, xt1 = 0.0f;
    int r = 0;
    unsigned scur = start;
    unsigned endr = segptr[s0];
    unsigned e = start;

#define FLUSH_REL {                                                          \
        float scl = (endr > scur) ? (1.0f / (float)(endr - scur)) : 0.0f;    \
        __builtin_nontemporal_store(                                         \
            (unsigned)f2b(a0 * scl) | ((unsigned)f2b(a1 * scl) << 16),       \
            arow + r * 64 + lane);                                           \
        a0 = 0.0f; a1 = 0.0f; scur = endr; ++r;                              \
        endr = (r < RR) ? segptr[s0 + r] : 0xFFFFFFFFu; }

#define ACCUM(rec, pv) {                                                     \
        float wgt = __uint_as_float((rec) & 0xFFFF0000u);                    \
        float vx = b2f((ushort)((pv) & 0xFFFFu));                            \
        float vy = b2f((ushort)((pv) >> 16));                                \
        a0 += vx; a1 += vy;                                                  \
        xt0 = fmaf(wgt, vx, xt0); xt1 = fmaf(wgt, vy, xt1); }

    while (e < endAll) {
        unsigned rem = endAll - e;
        int m = (rem > 4u) ? 4 : (int)rem;
        unsigned rec0 = 0, rec1 = 0, rec2 = 0, rec3 = 0;
        unsigned pv0 = 0, pv1 = 0, pv2 = 0, pv3 = 0;
        rec0 = srcw[e];
        if (m > 1) rec1 = srcw[e + 1];
        if (m > 2) rec2 = srcw[e + 2];
        if (m > 3) rec3 = srcw[e + 3];
        pv0 = ((const unsigned*)(xb + (size_t)(rec0 & 0xFFFFu) * DD))[lane];
        if (m > 1) pv1 = ((const unsigned*)(xb + (size_t)(rec1 & 0xFFFFu) * DD))[lane];
        if (m > 2) pv2 = ((const unsigned*)(xb + (size_t)(rec2 & 0xFFFFu) * DD))[lane];
        if (m > 3) pv3 = ((const unsigned*)(xb + (size_t)(rec3 & 0xFFFFu) * DD))[lane];

        while (e >= endr) FLUSH_REL;
        ACCUM(rec0, pv0); ++e;
        if (m > 1) { while (e >= endr) FLUSH_REL; ACCUM(rec1, pv1); ++e; }
        if (m > 2) { while (e >= endr) FLUSH_REL; ACCUM(rec2, pv2); ++e; }
        if (m > 3) { while (e >= endr) FLUSH_REL; ACCUM(rec3, pv3); ++e; }
    }
    while (r < RR) FLUSH_REL;

    float s2 = 1.0f / ((sumw + 1e-8f) * fmaxf((float)deg, 1.0f));
    __builtin_nontemporal_store(
        (unsigned)f2b(xt0 * s2) | ((unsigned)f2b(xt1 * s2) << 16),
        arow + RR * 64 + lane);
    __builtin_nontemporal_store(
        ((const unsigned*)(xb + (size_t)dst * DD))[lane],
        arow + (RR + 1) * 64 + lane);
#undef FLUSH_REL
#undef ACCUM
}

// ---------------- double-buffered tiled MFMA GEMM + bias/relu/LN ----------------
// Block: 256 thr / 64 rows x 128 cols, BK=64, 36 K-iters, 2x24 KB LDS ping-pong.
// One barrier per iter; prefetch(it+1) issued right after, overlapping HBM latency
// with the ds_read+MFMA phase. Grid 782 caps occupancy at ~3 blocks/CU either way.
__global__ __launch_bounds__(256) void k_fgemm(
    const ushort* __restrict__ A2, const ushort* __restrict__ Bt3,
    const float* __restrict__ bias, const float* __restrict__ tpb,
    const float* __restrict__ gamma, const float* __restrict__ beta,
    float* __restrict__ out)
{
    __shared__ unsigned As[2][2048];    // 2 x  8 KB: [row  64][8 chunks x 16B]
    __shared__ unsigned Bs[2][4096];    // 2 x 16 KB: [col 128][8 chunks x 16B]

    const int tid = threadIdx.x;
    const int w = tid >> 6, lane = tid & 63;
    const int quad = lane >> 4, l16 = lane & 15;
    const int n0 = blockIdx.x * 64;

    f32x4 acc[8];
#pragma unroll
    for (int ct = 0; ct < 8; ++ct) acc[ct] = (f32x4){0.f, 0.f, 0.f, 0.f};

    const int srow = lane >> 3;          // 0..7 within a staging inst group
    const int sc   = lane & 7;           // physical chunk

#define STAGE(buf, k0) {                                                       \
        _Pragma("unroll")                                                      \
        for (int i = 0; i < 2; ++i) {    /* A: 64 rows */                      \
            const int cid = i * 4 + w;                                         \
            const int row = cid * 8 + srow;                                    \
            const int ck  = sc ^ (row & 7);                                    \
            const ushort* ga = A2 + (size_t)(n0 + row) * KTOT + (k0) + ck * 8; \
            __builtin_amdgcn_global_load_lds(                                  \
                (const __attribute__((address_space(1))) unsigned*)ga,         \
                (__attribute__((address_space(3))) unsigned*)&As[buf][cid * 256], 16, 0, 0); \
        }                                                                      \
        _Pragma("unroll")                                                      \
        for (int i = 0; i < 4; ++i) {    /* B: 128 cols */                     \
            const int cid = i * 4 + w;                                         \
            const int row = cid * 8 + srow;                                    \
            const int ck  = sc ^ (row & 7);                                    \
            const ushort* gb = Bt3 + (size_t)row * KTOT + (k0) + ck * 8;       \
            __builtin_amdgcn_global_load_lds(                                  \
                (const __attribute__((address_space(1))) unsigned*)gb,         \
                (__attribute__((address_space(3))) unsigned*)&Bs[buf][cid * 256], 16, 0, 0); \
        }                                                                      \
    }

    STAGE(0, 0);
    const int NIT = KTOT / 64;
    for (int it = 0; it < NIT; ++it) {
        const int buf = it & 1;
        __syncthreads();                 // drains prefetch(it); guards buf^1 reuse
        if (it + 1 < NIT) STAGE(buf ^ 1, (it + 1) * 64);

        const int rA = w * 16 + l16;
        bf16x8 af[2];
#pragma unroll
        for (int h = 0; h < 2; ++h)
            af[h] = *(const bf16x8*)&As[buf][rA * 32 + (((h * 4 + quad) ^ (rA & 7)) << 2)];
#pragma unroll
        for (int ct = 0; ct < 8; ++ct) {
            const int rB = ct * 16 + l16;
            bf16x8 b0 = *(const bf16x8*)&Bs[buf][rB * 32 + ((quad ^ (rB & 7)) << 2)];
            bf16x8 b1 = *(const bf16x8*)&Bs[buf][rB * 32 + (((4 + quad) ^ (rB & 7)) << 2)];
            acc[ct] = __builtin_amdgcn_mfma_f32_16x16x32_bf16(af[0], b0, acc[ct], 0, 0, 0);
            acc[ct] = __builtin_amdgcn_mfma_f32_16x16x32_bf16(af[1], b1, acc[ct], 0, 0, 0);
        }
    }
#undef STAGE

    // ---- epilogue: bias + relu + LN (in-wave, rows rb = n0 + w*16) ----
    float bc[8], gc[8], be[8];
#pragma unroll
    for (int ct = 0; ct < 8; ++ct) {
        int col = ct * 16 + l16;
        bc[ct] = bias[col] + tpb[col];
        gc[ct] = gamma[col];
        be[ct] = beta[col];
    }
    float s[4] = {0, 0, 0, 0}, q[4] = {0, 0, 0, 0};
#pragma unroll
    for (int ct = 0; ct < 8; ++ct)
#pragma unroll
        for (int i = 0; i < 4; ++i) {
            float v = fmaxf(acc[ct][i] + bc[ct], 0.0f);
            acc[ct][i] = v;
            s[i] += v;
            q[i] = fmaf(v, v, q[i]);
        }
#pragma unroll
    for (int off = 1; off < 16; off <<= 1)
#pragma unroll
        for (int i = 0; i < 4; ++i) {
            s[i] += __shfl_xor(s[i], off, 64);
            q[i] += __shfl_xor(q[i], off, 64);
        }
#pragma unroll
    for (int i = 0; i < 4; ++i) {
        const int row = n0 + w * 16 + quad * 4 + i;
        float mu  = s[i] * (1.0f / DD);
        float var = q[i] * (1.0f / DD) - mu * mu;
        float inv = rsqrtf(var + 1e-5f);
        if (row < NN) {
#pragma unroll
            for (int ct = 0; ct < 8; ++ct)
                __builtin_nontemporal_store(
                    (acc[ct][i] - mu) * inv * gc[ct] + be[ct],
                    out + (size_t)row * DD + ct * 16 + l16);
        }
    }
}

extern "C" void kernel_launch(void* const* d_in, const int* in_sizes, int n_in,
                              void* d_out, int out_size, void* d_ws, size_t ws_size,
                              hipStream_t stream)
{
    const float* x     = (const float*)d_in[0];
    const int*   ei    = (const int*)d_in[1];
    const int*   etype = (const int*)d_in[2];
    const float* etime = (const float*)d_in[3];
    const float* basis = (const float*)d_in[4];
    const float* comp  = (const float*)d_in[5];
    const float* root  = (const float*)d_in[6];
    const float* bias  = (const float*)d_in[7];
    const float* tp_w  = (const float*)d_in[8];
    const float* tp_b  = (const float*)d_in[9];
    const float* gamma = (const float*)d_in[10];
    const float* beta  = (const float*)d_in[11];
    float* out = (float*)d_out;

    char* ws = (char*)d_ws;
    size_t off = 0;
    auto alloc = [&](size_t bytes) -> void* {
        void* p = ws + off;
        off = (off + bytes + 255) & ~(size_t)255;
        return p;
    };
    unsigned* red    = (unsigned*)alloc(64);
    unsigned* cnt    = (unsigned*)alloc((size_t)NSEG * 4);        //   3.2 MB
    unsigned* segptr = (unsigned*)alloc((size_t)NSEG * 4);        //   3.2 MB
    unsigned* part   = (unsigned*)alloc(1024 * 4);                //   4 KB
    unsigned* srcw   = (unsigned*)alloc((size_t)NE * 4);          //   6.4 MB
    ushort*   xb     = (ushort*)alloc((size_t)NN * DD * 2);       //  12.8 MB
    ushort*   Bt3    = (ushort*)alloc((size_t)DD * KTOT * 2);     //   0.59 MB
    ushort*   A2     = (ushort*)alloc((size_t)50048 * KTOT * 2);  // 230.6 MB (~256.8 MB total)
    (void)ws_size;

    const int* esrc = ei;
    const int* edst = ei + NE;

    hipLaunchKernelGGL(k_init, dim3(1), dim3(64), 0, stream, red);
    (void)hipMemsetAsync(cnt, 0, (size_t)NSEG * 4, stream);
    hipLaunchKernelGGL(k_pre1, dim3(1024), dim3(256), 0, stream,
                       etime, edst, etype, red, cnt);

    hipLaunchKernelGGL(k_scan1, dim3(NPART), dim3(1024), 0, stream, cnt, segptr, part);
    hipLaunchKernelGGL(k_scan2, dim3(1), dim3(1024), 0, stream, part);
    hipLaunchKernelGGL(k_scan3, dim3(NPART), dim3(1024), 0, stream, segptr, part);

    hipLaunchKernelGGL(k_pre2, dim3(1024), dim3(256), 0, stream,
                       esrc, edst, etype, etime, red, segptr, srcw);

    hipLaunchKernelGGL(k_prep, dim3((XB_ITEMS + DD * KTOT + 255) / 256), dim3(256), 0, stream,
                       x, basis, comp, root, tp_w, xb, Bt3);

    hipLaunchKernelGGL(k_gather, dim3((NN + 3) / 4), dim3(256), 0, stream,
                       xb, srcw, segptr, red, A2);

    hipLaunchKernelGGL(k_fgemm, dim3((50048 + 63) / 64), dim3(256), 0, stream,
                       A2, Bt3, bias, tp_b, gamma, beta, out);
}

// Round 15
// 477.032 us; speedup vs baseline: 1.1025x; 1.0107x over previous
//
#include <hip/hip_runtime.h>
#include <hip/hip_bf16.h>
#include <math.h>

#define NN 50000
#define DD 128
#define RR 16
#define NBASIS 10
#define NE 1600000
#define NSEG (NN * RR)                  // 800000 segments (dst,rel)
#define NPART ((NSEG + 1023) / 1024)    // 782
#define KTOT 2304                       // 18*128: 16 rel + time + root/x
#define DECAY 0.1f

typedef short bf16x8 __attribute__((ext_vector_type(8)));
typedef float f32x4 __attribute__((ext_vector_type(4)));

__device__ __forceinline__ ushort f2b(float f) {
    unsigned u = __float_as_uint(f);
    unsigned r = (u + 0x7FFFu + ((u >> 16) & 1u)) >> 16;
    return (ushort)r;
}
__device__ __forceinline__ float b2f(ushort u) {
    return __uint_as_float(((unsigned)u) << 16);
}

// ---------------- reduction slots ----------------
__global__ void k_init(unsigned* red) {
    if (threadIdx.x == 0) {
        red[0] = 0u;              // max(t) bits (t>=0: uint order == float order)
        red[1] = 0x7F800000u;     // min(t) = +inf
        ((float*)red)[2] = 0.0f;  // sum of unnormalized w
    }
}

// ---------------- grid-stride: edge_time min/max + segment histogram ----------------
// r11-proven inner form; one fire-and-forget atomic per edge per iter.
// (r13 lesson: 4-burst atomics per thread REGRESS scattered-atomic throughput.)
__global__ __launch_bounds__(256) void k_pre1(const float* __restrict__ t,
                                              const int* __restrict__ edst,
                                              const int* __restrict__ etype,
                                              unsigned* __restrict__ red,
                                              unsigned* __restrict__ cnt) {
    __shared__ float smx[4], smn[4];
    const int tid = threadIdx.x;
    float mx = 0.0f, mn = 1e30f;
    const int stride = gridDim.x * 256;
    for (int e = blockIdx.x * 256 + tid; e < NE; e += stride) {
        float v = __builtin_nontemporal_load(t + e);
        int d   = __builtin_nontemporal_load(edst + e);
        int ty  = __builtin_nontemporal_load(etype + e);
        mx = fmaxf(mx, v);
        mn = fminf(mn, v);
        atomicAdd(&cnt[d * RR + ty], 1u);
    }
    for (int o = 32; o >= 1; o >>= 1) {
        mx = fmaxf(mx, __shfl_down(mx, o, 64));
        mn = fminf(mn, __shfl_down(mn, o, 64));
    }
    if ((tid & 63) == 0) { smx[tid >> 6] = mx; smn[tid >> 6] = mn; }
    __syncthreads();
    if (tid == 0) {
        mx = fmaxf(fmaxf(smx[0], smx[1]), fmaxf(smx[2], smx[3]));
        mn = fminf(fminf(smn[0], smn[1]), fminf(smn[2], smn[3]));
        atomicMax(&red[0], __float_as_uint(mx));
        atomicMin(&red[1], __float_as_uint(mn));
    }
}

// ---------------- hierarchical exclusive scan over cnt[NSEG] ----------------
__global__ __launch_bounds__(1024) void k_scan1(const unsigned* __restrict__ cnt,
                                                unsigned* __restrict__ segptr,
                                                unsigned* __restrict__ part) {
    __shared__ unsigned sh[1024];
    int tid = threadIdx.x;
    int i = blockIdx.x * 1024 + tid;
    unsigned v = (i < NSEG) ? cnt[i] : 0u;
    sh[tid] = v;
    __syncthreads();
    for (int off = 1; off < 1024; off <<= 1) {
        unsigned t = (tid >= off) ? sh[tid - off] : 0u;
        __syncthreads();
        sh[tid] += t;
        __syncthreads();
    }
    if (i < NSEG) segptr[i] = sh[tid] - v;       // exclusive, block-local
    if (tid == 1023) part[blockIdx.x] = sh[1023];
}

__global__ __launch_bounds__(1024) void k_scan2(unsigned* __restrict__ part) {
    __shared__ unsigned sh[1024];
    int tid = threadIdx.x;
    unsigned v = (tid < NPART) ? part[tid] : 0u;
    sh[tid] = v;
    __syncthreads();
    for (int off = 1; off < 1024; off <<= 1) {
        unsigned t = (tid >= off) ? sh[tid - off] : 0u;
        __syncthreads();
        sh[tid] += t;
        __syncthreads();
    }
    if (tid < NPART) part[tid] = sh[tid] - v;    // exclusive
}

__global__ __launch_bounds__(1024) void k_scan3(unsigned* __restrict__ segptr,
                                                const unsigned* __restrict__ part) {
    int i = blockIdx.x * 1024 + threadIdx.x;
    if (i < NSEG) segptr[i] += part[i >> 10];
}

// ---------------- grid-stride: sum of weights + reorder into packed records ----------------
// r11-proven inner form. record = src(16) | bf16(w)(16). After: segptr[s] = END of seg s.
__global__ __launch_bounds__(256) void k_pre2(const int* __restrict__ esrc,
                                              const int* __restrict__ edst,
                                              const int* __restrict__ etype,
                                              const float* __restrict__ etime,
                                              unsigned* __restrict__ red,
                                              unsigned* __restrict__ segptr,
                                              unsigned* __restrict__ srcw) {
    __shared__ float ssum[4];
    const int tid = threadIdx.x;
    const float tmax = __uint_as_float(red[0]);
    const float tmin = __uint_as_float(red[1]);
    const float rtd = -DECAY / (tmax - tmin + 1e-8f);
    float s = 0.0f;
    const int stride = gridDim.x * 256;
    for (int e = blockIdx.x * 256 + tid; e < NE; e += stride) {
        float tv = __builtin_nontemporal_load(etime + e);
        int sv   = __builtin_nontemporal_load(esrc + e);
        int dv   = __builtin_nontemporal_load(edst + e);
        int yv   = __builtin_nontemporal_load(etype + e);
        float w = expf((tmax - tv) * rtd);
        s += w;
        int seg = dv * RR + yv;
        unsigned pos = atomicAdd(&segptr[seg], 1u);
        srcw[pos] = (unsigned)(sv & 0xFFFF) | ((unsigned)f2b(w) << 16);
    }
    for (int o = 32; o >= 1; o >>= 1) s += __shfl_down(s, o, 64);
    if ((tid & 63) == 0) ssum[tid >> 6] = s;
    __syncthreads();
    if (tid == 0)
        atomicAdd(((float*)red) + 2, ssum[0] + ssum[1] + ssum[2] + ssum[3]);
}

// ---------------- fused: x->bf16 and build Bt3[j][k] bf16 (k = r*128+d) ----------------
#define XB_ITEMS (NN * (DD / 4))
__global__ __launch_bounds__(256) void k_prep(const float* __restrict__ x,
                                              const float* __restrict__ basis,
                                              const float* __restrict__ comp,
                                              const float* __restrict__ root,
                                              const float* __restrict__ tp_w,
                                              ushort* __restrict__ xb,
                                              ushort* __restrict__ Bt3) {
    int idx = blockIdx.x * 256 + threadIdx.x;
    if (idx < XB_ITEMS) {
        float4 v = ((const float4*)x)[idx];
        ushort4 o;
        o.x = f2b(v.x); o.y = f2b(v.y); o.z = f2b(v.z); o.w = f2b(v.w);
        ((ushort4*)xb)[idx] = o;
        return;
    }
    int bidx = idx - XB_ITEMS;
    if (bidx >= DD * KTOT) return;
    int j = bidx / KTOT, k = bidx - j * KTOT;
    int r = k >> 7, d = k & 127;
    float v;
    if (r < RR) {
        v = 0.0f;
        for (int b = 0; b < NBASIS; ++b)
            v = fmaf(comp[r * NBASIS + b], basis[(b * DD + d) * DD + j], v);
    } else if (r == RR) {
        v = tp_w[d * DD + j];
    } else {
        v = root[d * DD + j];
    }
    Bt3[bidx] = f2b(v);
}

// ---------------- gather-aggregate: one wave per dst, SCALARIZED bookkeeping ----------------
__global__ __launch_bounds__(256) void k_gather(
    const ushort* __restrict__ xb, const unsigned* __restrict__ srcw,
    const unsigned* __restrict__ segptr, const unsigned* __restrict__ red,
    ushort* __restrict__ A2)
{
    const int wave = threadIdx.x >> 6, lane = threadIdx.x & 63;
    int dst0 = blockIdx.x * 4 + wave;
    if (dst0 >= NN) return;
    const int dst = __builtin_amdgcn_readfirstlane(dst0);
    const float sumw = ((const float*)red)[2];
    const unsigned s0 = (unsigned)dst * RR;
    const unsigned start = (dst == 0) ? 0u : segptr[s0 - 1];
    const unsigned endAll = segptr[s0 + RR - 1];
    const unsigned deg = endAll - start;
    unsigned* arow = (unsigned*)(A2 + (size_t)dst * KTOT);

    float a0 = 0.0f, a1 = 0.0f, xt0 = 0.0f, xt1 = 0.0f;
    int r = 0;
    unsigned scur = start;
    unsigned endr = segptr[s0];
    unsigned e = start;

#define FLUSH_REL {                                                          \
        float scl = (endr > scur) ? (1.0f / (float)(endr - scur)) : 0.0f;    \
        __builtin_nontemporal_store(                                         \
            (unsigned)f2b(a0 * scl) | ((unsigned)f2b(a1 * scl) << 16),       \
            arow + r * 64 + lane);                                           \
        a0 = 0.0f; a1 = 0.0f; scur = endr; ++r;                              \
        endr = (r < RR) ? segptr[s0 + r] : 0xFFFFFFFFu; }

#define ACCUM(rec, pv) {                                                     \
        float wgt = __uint_as_float((rec) & 0xFFFF0000u);                    \
        float vx = b2f((ushort)((pv) & 0xFFFFu));                            \
        float vy = b2f((ushort)((pv) >> 16));                                \
        a0 += vx; a1 += vy;                                                  \
        xt0 = fmaf(wgt, vx, xt0); xt1 = fmaf(wgt, vy, xt1); }

    while (e < endAll) {
        unsigned rem = endAll - e;
        int m = (rem > 4u) ? 4 : (int)rem;
        unsigned rec0 = 0, rec1 = 0, rec2 = 0, rec3 = 0;
        unsigned pv0 = 0, pv1 = 0, pv2 = 0, pv3 = 0;
        rec0 = srcw[e];
        if (m > 1) rec1 = srcw[e + 1];
        if (m > 2) rec2 = srcw[e + 2];
        if (m > 3) rec3 = srcw[e + 3];
        pv0 = ((const unsigned*)(xb + (size_t)(rec0 & 0xFFFFu) * DD))[lane];
        if (m > 1) pv1 = ((const unsigned*)(xb + (size_t)(rec1 & 0xFFFFu) * DD))[lane];
        if (m > 2) pv2 = ((const unsigned*)(xb + (size_t)(rec2 & 0xFFFFu) * DD))[lane];
        if (m > 3) pv3 = ((const unsigned*)(xb + (size_t)(rec3 & 0xFFFFu) * DD))[lane];

        while (e >= endr) FLUSH_REL;
        ACCUM(rec0, pv0); ++e;
        if (m > 1) { while (e >= endr) FLUSH_REL; ACCUM(rec1, pv1); ++e; }
        if (m > 2) { while (e >= endr) FLUSH_REL; ACCUM(rec2, pv2); ++e; }
        if (m > 3) { while (e >= endr) FLUSH_REL; ACCUM(rec3, pv3); ++e; }
    }
    while (r < RR) FLUSH_REL;

    float s2 = 1.0f / ((sumw + 1e-8f) * fmaxf((float)deg, 1.0f));
    __builtin_nontemporal_store(
        (unsigned)f2b(xt0 * s2) | ((unsigned)f2b(xt1 * s2) << 16),
        arow + RR * 64 + lane);
    __builtin_nontemporal_store(
        ((const unsigned*)(xb + (size_t)dst * DD))[lane],
        arow + (RR + 1) * 64 + lane);
#undef FLUSH_REL
#undef ACCUM
}

// ---------------- tiled MFMA GEMM, 32-row blocks for TLP + bias/relu/LN ----------------
// Single-buffer (r14 lesson: source-level dbuf regresses — compiler emits
// conservative vmcnt(0) before ds_read that includes the prefetch).
// Block: 256 thr / 32 rows x 128 cols, grid 1564 (~6 blocks/CU): latency hidden
// by other resident blocks computing while one drains its barrier.
// Wave w: rows (w&1)*16.., cols (w>>1)*64..; LN via one cross-wave LDS exchange.
__global__ __launch_bounds__(256) void k_fgemm(
    const ushort* __restrict__ A2, const ushort* __restrict__ Bt3,
    const float* __restrict__ bias, const float* __restrict__ tpb,
    const float* __restrict__ gamma, const float* __restrict__ beta,
    float* __restrict__ out)
{
    __shared__ unsigned As[1024];    //  4 KB: [row  32][8 chunks x 16B]
    __shared__ unsigned Bs[4096];    // 16 KB: [col 128][8 chunks x 16B]
    __shared__ float lnS[2][32], lnQ[2][32];

    const int tid = threadIdx.x;
    const int w = tid >> 6, lane = tid & 63;
    const int quad = lane >> 4, l16 = lane & 15;
    const int rh = w & 1, ch = w >> 1;
    const int n0 = blockIdx.x * 32;

    f32x4 acc[4];
#pragma unroll
    for (int ct = 0; ct < 4; ++ct) acc[ct] = (f32x4){0.f, 0.f, 0.f, 0.f};

    const int srow = lane >> 3;          // 0..7 within a staging inst group
    const int sc   = lane & 7;           // physical chunk
    for (int it = 0; it < KTOT / 64; ++it) {
        const int k0 = it * 64;
        __syncthreads();                 // protect LDS from previous iter's readers
        {   // A: 32 rows, one inst per wave
            const int row = w * 8 + srow;            // 0..31
            const int ck  = sc ^ (row & 7);          // swizzled global chunk
            const ushort* ga = A2 + (size_t)(n0 + row) * KTOT + k0 + ck * 8;
            __builtin_amdgcn_global_load_lds(
                (const __attribute__((address_space(1))) unsigned*)ga,
                (__attribute__((address_space(3))) unsigned*)&As[w * 256], 16, 0, 0);
        }
#pragma unroll
        for (int i = 0; i < 4; ++i) {    // B: 128 cols
            const int cid = i * 4 + w;               // 0..15
            const int row = cid * 8 + srow;          // 0..127
            const int ck  = sc ^ (row & 7);
            const ushort* gb = Bt3 + (size_t)row * KTOT + k0 + ck * 8;
            __builtin_amdgcn_global_load_lds(
                (const __attribute__((address_space(1))) unsigned*)gb,
                (__attribute__((address_space(3))) unsigned*)&Bs[cid * 256], 16, 0, 0);
        }
        __syncthreads();                 // drains vmcnt: tiles ready

        const int rA = rh * 16 + l16;
        bf16x8 af[2];
#pragma unroll
        for (int h = 0; h < 2; ++h)
            af[h] = *(const bf16x8*)&As[rA * 32 + (((h * 4 + quad) ^ (rA & 7)) << 2)];
#pragma unroll
        for (int ct = 0; ct < 4; ++ct) {
            const int rB = ch * 64 + ct * 16 + l16;
            bf16x8 b0 = *(const bf16x8*)&Bs[rB * 32 + ((quad ^ (rB & 7)) << 2)];
            bf16x8 b1 = *(const bf16x8*)&Bs[rB * 32 + (((4 + quad) ^ (rB & 7)) << 2)];
            acc[ct] = __builtin_amdgcn_mfma_f32_16x16x32_bf16(af[0], b0, acc[ct], 0, 0, 0);
            acc[ct] = __builtin_amdgcn_mfma_f32_16x16x32_bf16(af[1], b1, acc[ct], 0, 0, 0);
        }
    }

    // ---- epilogue: bias + relu, 64-col partials, cross-half LN, store ----
    float bc[4], gc[4], be[4];
#pragma unroll
    for (int ct = 0; ct < 4; ++ct) {
        int col = ch * 64 + ct * 16 + l16;
        bc[ct] = bias[col] + tpb[col];
        gc[ct] = gamma[col];
        be[ct] = beta[col];
    }
    float s[4] = {0, 0, 0, 0}, q[4] = {0, 0, 0, 0};
#pragma unroll
    for (int ct = 0; ct < 4; ++ct)
#pragma unroll
        for (int i = 0; i < 4; ++i) {
            float v = fmaxf(acc[ct][i] + bc[ct], 0.0f);
            acc[ct][i] = v;
            s[i] += v;
            q[i] = fmaf(v, v, q[i]);
        }
#pragma unroll
    for (int off = 1; off < 16; off <<= 1)
#pragma unroll
        for (int i = 0; i < 4; ++i) {
            s[i] += __shfl_xor(s[i], off, 64);
            q[i] += __shfl_xor(q[i], off, 64);
        }
    if (l16 == 0) {
#pragma unroll
        for (int i = 0; i < 4; ++i) {
            lnS[ch][rh * 16 + quad * 4 + i] = s[i];
            lnQ[ch][rh * 16 + quad * 4 + i] = q[i];
        }
    }
    __syncthreads();
#pragma unroll
    for (int i = 0; i < 4; ++i) {
        const int lrow = rh * 16 + quad * 4 + i;
        const int row = n0 + lrow;
        float S = lnS[0][lrow] + lnS[1][lrow];
        float Q = lnQ[0][lrow] + lnQ[1][lrow];
        float mu  = S * (1.0f / DD);
        float var = Q * (1.0f / DD) - mu * mu;
        float inv = rsqrtf(var + 1e-5f);
        if (row < NN) {
#pragma unroll
            for (int ct = 0; ct < 4; ++ct)
                __builtin_nontemporal_store(
                    (acc[ct][i] - mu) * inv * gc[ct] + be[ct],
                    out + (size_t)row * DD + ch * 64 + ct * 16 + l16);
        }
    }
}

extern "C" void kernel_launch(void* const* d_in, const int* in_sizes, int n_in,
                              void* d_out, int out_size, void* d_ws, size_t ws_size,
                              hipStream_t stream)
{
    const float* x     = (const float*)d_in[0];
    const int*   ei    = (const int*)d_in[1];
    const int*   etype = (const int*)d_in[2];
    const float* etime = (const float*)d_in[3];
    const float* basis = (const float*)d_in[4];
    const float* comp  = (const float*)d_in[5];
    const float* root  = (const float*)d_in[6];
    const float* bias  = (const float*)d_in[7];
    const float* tp_w  = (const float*)d_in[8];
    const float* tp_b  = (const float*)d_in[9];
    const float* gamma = (const float*)d_in[10];
    const float* beta  = (const float*)d_in[11];
    float* out = (float*)d_out;

    char* ws = (char*)d_ws;
    size_t off = 0;
    auto alloc = [&](size_t bytes) -> void* {
        void* p = ws + off;
        off = (off + bytes + 255) & ~(size_t)255;
        return p;
    };
    unsigned* red    = (unsigned*)alloc(64);
    unsigned* cnt    = (unsigned*)alloc((size_t)NSEG * 4);        //   3.2 MB
    unsigned* segptr = (unsigned*)alloc((size_t)NSEG * 4);        //   3.2 MB
    unsigned* part   = (unsigned*)alloc(1024 * 4);                //   4 KB
    unsigned* srcw   = (unsigned*)alloc((size_t)NE * 4);          //   6.4 MB
    ushort*   xb     = (ushort*)alloc((size_t)NN * DD * 2);       //  12.8 MB
    ushort*   Bt3    = (ushort*)alloc((size_t)DD * KTOT * 2);     //   0.59 MB
    ushort*   A2     = (ushort*)alloc((size_t)50048 * KTOT * 2);  // 230.6 MB (~256.8 MB total)
    (void)ws_size;

    const int* esrc = ei;
    const int* edst = ei + NE;

    hipLaunchKernelGGL(k_init, dim3(1), dim3(64), 0, stream, red);
    (void)hipMemsetAsync(cnt, 0, (size_t)NSEG * 4, stream);
    hipLaunchKernelGGL(k_pre1, dim3(2048), dim3(256), 0, stream,
                       etime, edst, etype, red, cnt);

    hipLaunchKernelGGL(k_scan1, dim3(NPART), dim3(1024), 0, stream, cnt, segptr, part);
    hipLaunchKernelGGL(k_scan2, dim3(1), dim3(1024), 0, stream, part);
    hipLaunchKernelGGL(k_scan3, dim3(NPART), dim3(1024), 0, stream, segptr, part);

    hipLaunchKernelGGL(k_pre2, dim3(2048), dim3(256), 0, stream,
                       esrc, edst, etype, etime, red, segptr, srcw);

    hipLaunchKernelGGL(k_prep, dim3((XB_ITEMS + DD * KTOT + 255) / 256), dim3(256), 0, stream,
                       x, basis, comp, root, tp_w, xb, Bt3);

    hipLaunchKernelGGL(k_gather, dim3((NN + 3) / 4), dim3(256), 0, stream,
                       xb, srcw, segptr, red, A2);

    hipLaunchKernelGGL(k_fgemm, dim3(50048 / 32), dim3(256), 0, stream,
                       A2, Bt3, bias, tp_b, gamma, beta, out);
}

// Round 16
// 449.985 us; speedup vs baseline: 1.1688x; 1.0601x over previous
//
#include <hip/hip_runtime.h>
#include <hip/hip_bf16.h>
#include <math.h>

#define NN 50000
#define DD 128
#define RR 16
#define NBASIS 10
#define NE 1600000
#define NSEG (NN * RR)                  // 800000 segments (dst,rel)
#define NPART ((NSEG + 1023) / 1024)    // 782
#define KTOT 2304                       // 18*128: 16 rel + time + root/x
#define DECAY 0.1f

typedef short bf16x8 __attribute__((ext_vector_type(8)));
typedef float f32x4 __attribute__((ext_vector_type(4)));

__device__ __forceinline__ ushort f2b(float f) {
    unsigned u = __float_as_uint(f);
    unsigned r = (u + 0x7FFFu + ((u >> 16) & 1u)) >> 16;
    return (ushort)r;
}
__device__ __forceinline__ float b2f(ushort u) {
    return __uint_as_float(((unsigned)u) << 16);
}

// ---------------- reduction slots ----------------
__global__ void k_init(unsigned* red) {
    if (threadIdx.x == 0) {
        red[0] = 0u;              // max(t) bits (t>=0: uint order == float order)
        red[1] = 0x7F800000u;     // min(t) = +inf
        ((float*)red)[2] = 0.0f;  // sum of unnormalized w
    }
}

// ---------------- grid-stride: edge_time min/max + segment histogram ----------------
// r11-measured optimum: grid 1024, one fire-and-forget atomic per edge per iter.
// (r13: 4-burst atomics regress; r15: grid 2048 regresses.)
__global__ __launch_bounds__(256) void k_pre1(const float* __restrict__ t,
                                              const int* __restrict__ edst,
                                              const int* __restrict__ etype,
                                              unsigned* __restrict__ red,
                                              unsigned* __restrict__ cnt) {
    __shared__ float smx[4], smn[4];
    const int tid = threadIdx.x;
    float mx = 0.0f, mn = 1e30f;
    const int stride = gridDim.x * 256;
    for (int e = blockIdx.x * 256 + tid; e < NE; e += stride) {
        float v = __builtin_nontemporal_load(t + e);
        int d   = __builtin_nontemporal_load(edst + e);
        int ty  = __builtin_nontemporal_load(etype + e);
        mx = fmaxf(mx, v);
        mn = fminf(mn, v);
        atomicAdd(&cnt[d * RR + ty], 1u);
    }
    for (int o = 32; o >= 1; o >>= 1) {
        mx = fmaxf(mx, __shfl_down(mx, o, 64));
        mn = fminf(mn, __shfl_down(mn, o, 64));
    }
    if ((tid & 63) == 0) { smx[tid >> 6] = mx; smn[tid >> 6] = mn; }
    __syncthreads();
    if (tid == 0) {
        mx = fmaxf(fmaxf(smx[0], smx[1]), fmaxf(smx[2], smx[3]));
        mn = fminf(fminf(smn[0], smn[1]), fminf(smn[2], smn[3]));
        atomicMax(&red[0], __float_as_uint(mx));
        atomicMin(&red[1], __float_as_uint(mn));
    }
}

// ---------------- hierarchical exclusive scan over cnt[NSEG] ----------------
__global__ __launch_bounds__(1024) void k_scan1(const unsigned* __restrict__ cnt,
                                                unsigned* __restrict__ segptr,
                                                unsigned* __restrict__ part) {
    __shared__ unsigned sh[1024];
    int tid = threadIdx.x;
    int i = blockIdx.x * 1024 + tid;
    unsigned v = (i < NSEG) ? cnt[i] : 0u;
    sh[tid] = v;
    __syncthreads();
    for (int off = 1; off < 1024; off <<= 1) {
        unsigned t = (tid >= off) ? sh[tid - off] : 0u;
        __syncthreads();
        sh[tid] += t;
        __syncthreads();
    }
    if (i < NSEG) segptr[i] = sh[tid] - v;       // exclusive, block-local
    if (tid == 1023) part[blockIdx.x] = sh[1023];
}

__global__ __launch_bounds__(1024) void k_scan2(unsigned* __restrict__ part) {
    __shared__ unsigned sh[1024];
    int tid = threadIdx.x;
    unsigned v = (tid < NPART) ? part[tid] : 0u;
    sh[tid] = v;
    __syncthreads();
    for (int off = 1; off < 1024; off <<= 1) {
        unsigned t = (tid >= off) ? sh[tid - off] : 0u;
        __syncthreads();
        sh[tid] += t;
        __syncthreads();
    }
    if (tid < NPART) part[tid] = sh[tid] - v;    // exclusive
}

__global__ __launch_bounds__(1024) void k_scan3(unsigned* __restrict__ segptr,
                                                const unsigned* __restrict__ part) {
    int i = blockIdx.x * 1024 + threadIdx.x;
    if (i < NSEG) segptr[i] += part[i >> 10];
}

// ---------------- grid-stride: sum of weights + reorder into packed records ----------------
// r11-measured optimum (grid 1024). record = src(16) | bf16(w)(16).
// After: segptr[s] = END of seg s.
__global__ __launch_bounds__(256) void k_pre2(const int* __restrict__ esrc,
                                              const int* __restrict__ edst,
                                              const int* __restrict__ etype,
                                              const float* __restrict__ etime,
                                              unsigned* __restrict__ red,
                                              unsigned* __restrict__ segptr,
                                              unsigned* __restrict__ srcw) {
    __shared__ float ssum[4];
    const int tid = threadIdx.x;
    const float tmax = __uint_as_float(red[0]);
    const float tmin = __uint_as_float(red[1]);
    const float rtd = -DECAY / (tmax - tmin + 1e-8f);
    float s = 0.0f;
    const int stride = gridDim.x * 256;
    for (int e = blockIdx.x * 256 + tid; e < NE; e += stride) {
        float tv = __builtin_nontemporal_load(etime + e);
        int sv   = __builtin_nontemporal_load(esrc + e);
        int dv   = __builtin_nontemporal_load(edst + e);
        int yv   = __builtin_nontemporal_load(etype + e);
        float w = expf((tmax - tv) * rtd);
        s += w;
        int seg = dv * RR + yv;
        unsigned pos = atomicAdd(&segptr[seg], 1u);
        srcw[pos] = (unsigned)(sv & 0xFFFF) | ((unsigned)f2b(w) << 16);
    }
    for (int o = 32; o >= 1; o >>= 1) s += __shfl_down(s, o, 64);
    if ((tid & 63) == 0) ssum[tid >> 6] = s;
    __syncthreads();
    if (tid == 0)
        atomicAdd(((float*)red) + 2, ssum[0] + ssum[1] + ssum[2] + ssum[3]);
}

// ---------------- fused: x->bf16 and build Bt3[j][k] bf16 (k = r*128+d) ----------------
#define XB_ITEMS (NN * (DD / 4))
__global__ __launch_bounds__(256) void k_prep(const float* __restrict__ x,
                                              const float* __restrict__ basis,
                                              const float* __restrict__ comp,
                                              const float* __restrict__ root,
                                              const float* __restrict__ tp_w,
                                              ushort* __restrict__ xb,
                                              ushort* __restrict__ Bt3) {
    int idx = blockIdx.x * 256 + threadIdx.x;
    if (idx < XB_ITEMS) {
        float4 v = ((const float4*)x)[idx];
        ushort4 o;
        o.x = f2b(v.x); o.y = f2b(v.y); o.z = f2b(v.z); o.w = f2b(v.w);
        ((ushort4*)xb)[idx] = o;
        return;
    }
    int bidx = idx - XB_ITEMS;
    if (bidx >= DD * KTOT) return;
    int j = bidx / KTOT, k = bidx - j * KTOT;
    int r = k >> 7, d = k & 127;
    float v;
    if (r < RR) {
        v = 0.0f;
        for (int b = 0; b < NBASIS; ++b)
            v = fmaf(comp[r * NBASIS + b], basis[(b * DD + d) * DD + j], v);
    } else if (r == RR) {
        v = tp_w[d * DD + j];
    } else {
        v = root[d * DD + j];
    }
    Bt3[bidx] = f2b(v);
}

// ---------------- gather-aggregate: one wave per dst, SCALARIZED bookkeeping ----------------
__global__ __launch_bounds__(256) void k_gather(
    const ushort* __restrict__ xb, const unsigned* __restrict__ srcw,
    const unsigned* __restrict__ segptr, const unsigned* __restrict__ red,
    ushort* __restrict__ A2)
{
    const int wave = threadIdx.x >> 6, lane = threadIdx.x & 63;
    int dst0 = blockIdx.x * 4 + wave;
    if (dst0 >= NN) return;
    const int dst = __builtin_amdgcn_readfirstlane(dst0);
    const float sumw = ((const float*)red)[2];
    const unsigned s0 = (unsigned)dst * RR;
    const unsigned start = (dst == 0) ? 0u : segptr[s0 - 1];
    const unsigned endAll = segptr[s0 + RR - 1];
    const unsigned deg = endAll - start;
    unsigned* arow = (unsigned*)(A2 + (size_t)dst * KTOT);

    float a0 = 0.0f, a1 = 0.0f, xt0 = 0.0f, xt1 = 0.0f;
    int r = 0;
    unsigned scur = start;
    unsigned endr = segptr[s0];
    unsigned e = start;

#define FLUSH_REL {                                                          \
        float scl = (endr > scur) ? (1.0f / (float)(endr - scur)) : 0.0f;    \
        __builtin_nontemporal_store(                                         \
            (unsigned)f2b(a0 * scl) | ((unsigned)f2b(a1 * scl) << 16),       \
            arow + r * 64 + lane);                                           \
        a0 = 0.0f; a1 = 0.0f; scur = endr; ++r;                              \
        endr = (r < RR) ? segptr[s0 + r] : 0xFFFFFFFFu; }

#define ACCUM(rec, pv) {                                                     \
        float wgt = __uint_as_float((rec) & 0xFFFF0000u);                    \
        float vx = b2f((ushort)((pv) & 0xFFFFu));                            \
        float vy = b2f((ushort)((pv) >> 16));                                \
        a0 += vx; a1 += vy;                                                  \
        xt0 = fmaf(wgt, vx, xt0); xt1 = fmaf(wgt, vy, xt1); }

    while (e < endAll) {
        unsigned rem = endAll - e;
        int m = (rem > 4u) ? 4 : (int)rem;
        unsigned rec0 = 0, rec1 = 0, rec2 = 0, rec3 = 0;
        unsigned pv0 = 0, pv1 = 0, pv2 = 0, pv3 = 0;
        rec0 = srcw[e];
        if (m > 1) rec1 = srcw[e + 1];
        if (m > 2) rec2 = srcw[e + 2];
        if (m > 3) rec3 = srcw[e + 3];
        pv0 = ((const unsigned*)(xb + (size_t)(rec0 & 0xFFFFu) * DD))[lane];
        if (m > 1) pv1 = ((const unsigned*)(xb + (size_t)(rec1 & 0xFFFFu) * DD))[lane];
        if (m > 2) pv2 = ((const unsigned*)(xb + (size_t)(rec2 & 0xFFFFu) * DD))[lane];
        if (m > 3) pv3 = ((const unsigned*)(xb + (size_t)(rec3 & 0xFFFFu) * DD))[lane];

        while (e >= endr) FLUSH_REL;
        ACCUM(rec0, pv0); ++e;
        if (m > 1) { while (e >= endr) FLUSH_REL; ACCUM(rec1, pv1); ++e; }
        if (m > 2) { while (e >= endr) FLUSH_REL; ACCUM(rec2, pv2); ++e; }
        if (m > 3) { while (e >= endr) FLUSH_REL; ACCUM(rec3, pv3); ++e; }
    }
    while (r < RR) FLUSH_REL;

    float s2 = 1.0f / ((sumw + 1e-8f) * fmaxf((float)deg, 1.0f));
    __builtin_nontemporal_store(
        (unsigned)f2b(xt0 * s2) | ((unsigned)f2b(xt1 * s2) << 16),
        arow + RR * 64 + lane);
    __builtin_nontemporal_store(
        ((const unsigned*)(xb + (size_t)dst * DD))[lane],
        arow + (RR + 1) * 64 + lane);
#undef FLUSH_REL
#undef ACCUM
}

// ---------------- tiled MFMA GEMM: B-in-LDS, A register-prefetched ----------------
// Block: 256 thr / 64 rows x 128 cols, grid 782 (r11-measured best tile/grid).
// Key change vs r11: only B (L2-resident, fast) goes through LDS + barrier;
// A fragments (HBM/L3, slow) load directly into registers, prefetched one
// iteration ahead so their latency overlaps compute. Register loads are
// per-register waitcnt-tracked, avoiding the r14 LDS-dbuf vmcnt(0) trap.
__global__ __launch_bounds__(256) void k_fgemm(
    const ushort* __restrict__ A2, const ushort* __restrict__ Bt3,
    const float* __restrict__ bias, const float* __restrict__ tpb,
    const float* __restrict__ gamma, const float* __restrict__ beta,
    float* __restrict__ out)
{
    __shared__ unsigned Bs[4096];    // 16 KB: [col 128][8 chunks x 16B]

    const int tid = threadIdx.x;
    const int w = tid >> 6, lane = tid & 63;
    const int quad = lane >> 4, l16 = lane & 15;
    const int n0 = blockIdx.x * 64;

    f32x4 acc[8];
#pragma unroll
    for (int ct = 0; ct < 8; ++ct) acc[ct] = (f32x4){0.f, 0.f, 0.f, 0.f};

    // A fragment source: this lane's row, A[m=l16][k=quad*8+j]
    const ushort* arow = A2 + (size_t)(n0 + w * 16 + l16) * KTOT + quad * 8;

    const int srow = lane >> 3;          // 0..7 within a staging inst group
    const int sc   = lane & 7;           // physical chunk

    bf16x8 afp0 = *(const bf16x8*)(arow);         // prefetch A(it=0)
    bf16x8 afp1 = *(const bf16x8*)(arow + 32);

    const int NIT = KTOT / 64;
    for (int it = 0; it < NIT; ++it) {
        const int k0 = it * 64;
        __syncthreads();                 // guard Bs overwrite (prev readers done)
#pragma unroll
        for (int i = 0; i < 4; ++i) {    // B: 128 cols
            const int cid = i * 4 + w;               // 0..15
            const int row = cid * 8 + srow;          // 0..127
            const int ck  = sc ^ (row & 7);          // swizzled global chunk
            const ushort* gb = Bt3 + (size_t)row * KTOT + k0 + ck * 8;
            __builtin_amdgcn_global_load_lds(
                (const __attribute__((address_space(1))) unsigned*)gb,
                (__attribute__((address_space(3))) unsigned*)&Bs[cid * 256], 16, 0, 0);
        }
        __syncthreads();                 // drain: Bs ready (afp also complete)

        bf16x8 af0 = afp0, af1 = afp1;
        if (it + 1 < NIT) {              // prefetch A(it+1): overlaps compute below
            afp0 = *(const bf16x8*)(arow + (it + 1) * 64);
            afp1 = *(const bf16x8*)(arow + (it + 1) * 64 + 32);
        }
#pragma unroll
        for (int ct = 0; ct < 8; ++ct) {
            const int rB = ct * 16 + l16;
            bf16x8 b0 = *(const bf16x8*)&Bs[rB * 32 + ((quad ^ (rB & 7)) << 2)];
            bf16x8 b1 = *(const bf16x8*)&Bs[rB * 32 + (((4 + quad) ^ (rB & 7)) << 2)];
            acc[ct] = __builtin_amdgcn_mfma_f32_16x16x32_bf16(af0, b0, acc[ct], 0, 0, 0);
            acc[ct] = __builtin_amdgcn_mfma_f32_16x16x32_bf16(af1, b1, acc[ct], 0, 0, 0);
        }
    }

    // ---- epilogue: bias + relu + LN (in-wave, rows rb = n0 + w*16) ----
    float bc[8], gc[8], be[8];
#pragma unroll
    for (int ct = 0; ct < 8; ++ct) {
        int col = ct * 16 + l16;
        bc[ct] = bias[col] + tpb[col];
        gc[ct] = gamma[col];
        be[ct] = beta[col];
    }
    float s[4] = {0, 0, 0, 0}, q[4] = {0, 0, 0, 0};
#pragma unroll
    for (int ct = 0; ct < 8; ++ct)
#pragma unroll
        for (int i = 0; i < 4; ++i) {
            float v = fmaxf(acc[ct][i] + bc[ct], 0.0f);
            acc[ct][i] = v;
            s[i] += v;
            q[i] = fmaf(v, v, q[i]);
        }
#pragma unroll
    for (int off = 1; off < 16; off <<= 1)
#pragma unroll
        for (int i = 0; i < 4; ++i) {
            s[i] += __shfl_xor(s[i], off, 64);
            q[i] += __shfl_xor(q[i], off, 64);
        }
#pragma unroll
    for (int i = 0; i < 4; ++i) {
        const int row = n0 + w * 16 + quad * 4 + i;
        float mu  = s[i] * (1.0f / DD);
        float var = q[i] * (1.0f / DD) - mu * mu;
        float inv = rsqrtf(var + 1e-5f);
        if (row < NN) {
#pragma unroll
            for (int ct = 0; ct < 8; ++ct)
                __builtin_nontemporal_store(
                    (acc[ct][i] - mu) * inv * gc[ct] + be[ct],
                    out + (size_t)row * DD + ct * 16 + l16);
        }
    }
}

extern "C" void kernel_launch(void* const* d_in, const int* in_sizes, int n_in,
                              void* d_out, int out_size, void* d_ws, size_t ws_size,
                              hipStream_t stream)
{
    const float* x     = (const float*)d_in[0];
    const int*   ei    = (const int*)d_in[1];
    const int*   etype = (const int*)d_in[2];
    const float* etime = (const float*)d_in[3];
    const float* basis = (const float*)d_in[4];
    const float* comp  = (const float*)d_in[5];
    const float* root  = (const float*)d_in[6];
    const float* bias  = (const float*)d_in[7];
    const float* tp_w  = (const float*)d_in[8];
    const float* tp_b  = (const float*)d_in[9];
    const float* gamma = (const float*)d_in[10];
    const float* beta  = (const float*)d_in[11];
    float* out = (float*)d_out;

    char* ws = (char*)d_ws;
    size_t off = 0;
    auto alloc = [&](size_t bytes) -> void* {
        void* p = ws + off;
        off = (off + bytes + 255) & ~(size_t)255;
        return p;
    };
    unsigned* red    = (unsigned*)alloc(64);
    unsigned* cnt    = (unsigned*)alloc((size_t)NSEG * 4);        //   3.2 MB
    unsigned* segptr = (unsigned*)alloc((size_t)NSEG * 4);        //   3.2 MB
    unsigned* part   = (unsigned*)alloc(1024 * 4);                //   4 KB
    unsigned* srcw   = (unsigned*)alloc((size_t)NE * 4);          //   6.4 MB
    ushort*   xb     = (ushort*)alloc((size_t)NN * DD * 2);       //  12.8 MB
    ushort*   Bt3    = (ushort*)alloc((size_t)DD * KTOT * 2);     //   0.59 MB
    ushort*   A2     = (ushort*)alloc((size_t)50048 * KTOT * 2);  // 230.6 MB (~256.8 MB total)
    (void)ws_size;

    const int* esrc = ei;
    const int* edst = ei + NE;

    hipLaunchKernelGGL(k_init, dim3(1), dim3(64), 0, stream, red);
    (void)hipMemsetAsync(cnt, 0, (size_t)NSEG * 4, stream);
    hipLaunchKernelGGL(k_pre1, dim3(1024), dim3(256), 0, stream,
                       etime, edst, etype, red, cnt);

    hipLaunchKernelGGL(k_scan1, dim3(NPART), dim3(1024), 0, stream, cnt, segptr, part);
    hipLaunchKernelGGL(k_scan2, dim3(1), dim3(1024), 0, stream, part);
    hipLaunchKernelGGL(k_scan3, dim3(NPART), dim3(1024), 0, stream, segptr, part);

    hipLaunchKernelGGL(k_pre2, dim3(1024), dim3(256), 0, stream,
                       esrc, edst, etype, etime, red, segptr, srcw);

    hipLaunchKernelGGL(k_prep, dim3((XB_ITEMS + DD * KTOT + 255) / 256), dim3(256), 0, stream,
                       x, basis, comp, root, tp_w, xb, Bt3);

    hipLaunchKernelGGL(k_gather, dim3((NN + 3) / 4), dim3(256), 0, stream,
                       xb, srcw, segptr, red, A2);

    hipLaunchKernelGGL(k_fgemm, dim3((50048 + 63) / 64), dim3(256), 0, stream,
                       A2, Bt3, bias, tp_b, gamma, beta, out);
}